// Round 1
// baseline (48.514 us; speedup 1.0000x reference)
//
#include <hip/hip_runtime.h>
#include <math.h>

#define EPS 1e-5f

// One block per batch row. Each block redundantly rebuilds the 64-token
// table (embed -> MLP -> residual -> layernorm -> hs, score) in LDS, then
// histograms its sequence row, derives slot counts per token, and does the
// softmax-attention epilogue. Total per-block FMA ~1M (U/H matmuls), which
// at 128 lanes/cyc/CU is ~8K cycles -- the VALU floor for full redundancy.
__global__ __launch_bounds__(512) void slot_fused(
    const int* __restrict__ seq,
    const float* __restrict__ embed,
    const float* __restrict__ W1, const float* __restrict__ b1,
    const float* __restrict__ W2, const float* __restrict__ b2,
    const float* __restrict__ gamma, const float* __restrict__ beta,
    const float* __restrict__ Wq, const float* __restrict__ bq,
    const float* __restrict__ Wo, const float* __restrict__ bo,
    float* __restrict__ out)
{
    __shared__ float E[64][64];     // embed rows per token
    __shared__ float U[64][128];    // relu(E@W1+b1)
    __shared__ float Hh[64][65];    // E + U@W2 + b2   (+1 pad: row-per-lane reads)
    __shared__ float HS[64][65];    // layernormed     (+1 pad)
    __shared__ float mu_s[64];
    __shared__ float rstd_s[64];
    __shared__ float sc[64];        // gate score per token
    __shared__ int   hist[8][64];   // per-wave sub-histograms
    __shared__ int   cnt[64];       // selected slot count per token
    __shared__ float qv[64];        // q = HS[t_last]@Wq + bq
    __shared__ float wgt[64];       // softmax weights (with multiplicity)
    __shared__ float ctx[64];
    __shared__ int   tlast;

    const int tid  = threadIdx.x;
    const int wave = tid >> 6;
    const int b    = blockIdx.x;
    const int* row = seq + b * 4096;

    // ---- init: zero sub-hists, load embed table, grab last token ----
    if (tid < 64) {
        #pragma unroll
        for (int w = 0; w < 8; ++w) hist[w][tid] = 0;
    }
    for (int i = tid; i < 64 * 64; i += 512) E[i >> 6][i & 63] = embed[i];
    if (tid == 0) tlast = row[4095];
    __syncthreads();

    // ---- histogram positions 0..4092 (content = hs[:, :-3]) ----
    // 4093 = 1023 * int4 + 1 scalar
    for (int i = tid; i < 1023; i += 512) {
        int4 v = reinterpret_cast<const int4*>(row)[i];
        atomicAdd(&hist[wave][v.x], 1);
        atomicAdd(&hist[wave][v.y], 1);
        atomicAdd(&hist[wave][v.z], 1);
        atomicAdd(&hist[wave][v.w], 1);
    }
    if (tid == 0) atomicAdd(&hist[0][row[4092]], 1);

    // ---- U = relu(E @ W1 + b1), (64 x 128) ----
    for (int i = tid; i < 64 * 128; i += 512) {
        int t = i >> 7, k = i & 127;
        float acc = b1[k];
        #pragma unroll 8
        for (int j = 0; j < 64; ++j) acc = fmaf(E[t][j], W1[j * 128 + k], acc);
        U[t][k] = fmaxf(acc, 0.f);
    }
    __syncthreads();   // U ready; histogram atomics also complete

    // ---- H = E + U @ W2 + b2, (64 x 64); merge hist in parallel ----
    for (int i = tid; i < 64 * 64; i += 512) {
        int t = i >> 6, j = i & 63;
        float acc = b2[j];
        #pragma unroll 8
        for (int k = 0; k < 128; ++k) acc = fmaf(U[t][k], W2[k * 64 + j], acc);
        Hh[t][j] = E[t][j] + acc;
    }
    if (tid < 64) {
        int s = hist[0][tid];
        #pragma unroll
        for (int w = 1; w < 8; ++w) s += hist[w][tid];
        hist[0][tid] = s;
    }
    __syncthreads();

    // ---- layernorm stats (one lane per token) ----
    if (tid < 64) {
        float s = 0.f;
        #pragma unroll 8
        for (int j = 0; j < 64; ++j) s += Hh[tid][j];
        float mu = s * (1.f / 64.f);
        float v = 0.f;
        #pragma unroll 8
        for (int j = 0; j < 64; ++j) { float d = Hh[tid][j] - mu; v = fmaf(d, d, v); }
        v *= (1.f / 64.f);
        mu_s[tid]   = mu;
        rstd_s[tid] = rsqrtf(v + EPS);
    }
    __syncthreads();

    // ---- HS = (H - mu) * rstd * gamma + beta ----
    for (int i = tid; i < 64 * 64; i += 512) {
        int t = i >> 6, j = i & 63;
        HS[t][j] = (Hh[t][j] - mu_s[t]) * rstd_s[t] * gamma[j] + beta[j];
    }
    __syncthreads();

    // ---- gate score per token: ||HS[t]|| ----
    if (tid < 64) {
        float ss = 0.f;
        #pragma unroll 8
        for (int j = 0; j < 64; ++j) ss = fmaf(HS[tid][j], HS[tid][j], ss);
        sc[tid] = sqrtf(ss);
    }
    __syncthreads();

    // ---- slot counts: greedy top-64 positions == greedy over tokens by
    //      descending score (ties: lower token id ~ lower first position;
    //      exact inter-token score ties are measure-zero) ----
    if (tid < 64) {
        float s = sc[tid];
        int S = 0;   // total occurrences of tokens ranked strictly before me
        for (int t2 = 0; t2 < 64; ++t2) {
            float s2 = sc[t2];
            bool before = (s2 > s) || (s2 == s && t2 < tid);
            if (before) S += hist[0][t2];
        }
        int rem = 64 - S;
        rem = rem < 0 ? 0 : rem;
        int h = hist[0][tid];
        cnt[tid] = h < rem ? h : rem;
    }
    __syncthreads();

    // ---- q = HS[t_last] @ Wq + bq ----
    if (tid < 64) {
        float acc = bq[tid];
        const int tl = tlast;
        #pragma unroll 8
        for (int k = 0; k < 64; ++k) acc = fmaf(HS[tl][k], Wq[k * 64 + tid], acc);
        qv[tid] = acc;
    }
    __syncthreads();

    // ---- logits + softmax with multiplicity (wave 0) ----
    if (tid < 64) {
        float acc = 0.f;
        #pragma unroll 8
        for (int k = 0; k < 64; ++k) acc = fmaf(qv[k], HS[tid][k], acc);
        float logit = acc * 0.125f;             // / sqrt(64)
        int c = cnt[tid];
        float lm = (c > 0) ? logit : -1e30f;
        #pragma unroll
        for (int off = 1; off < 64; off <<= 1) lm = fmaxf(lm, __shfl_xor(lm, off));
        float wv = (c > 0) ? (float)c * __expf(logit - lm) : 0.f;
        float z = wv;
        #pragma unroll
        for (int off = 1; off < 64; off <<= 1) z += __shfl_xor(z, off);
        wgt[tid] = wv / z;
    }
    __syncthreads();

    // ---- ctx = sum_t w_t * HS[t] ----
    if (tid < 64) {
        float acc = 0.f;
        #pragma unroll 8
        for (int t = 0; t < 64; ++t) acc = fmaf(wgt[t], HS[t][tid], acc);
        ctx[tid] = acc;
    }
    __syncthreads();

    // ---- out = ctx @ Wo + bo ----
    if (tid < 64) {
        float acc = bo[tid];
        #pragma unroll 8
        for (int k = 0; k < 64; ++k) acc = fmaf(ctx[k], Wo[k * 64 + tid], acc);
        out[b * 64 + tid] = acc;
    }
}

extern "C" void kernel_launch(void* const* d_in, const int* in_sizes, int n_in,
                              void* d_out, int out_size, void* d_ws, size_t ws_size,
                              hipStream_t stream) {
    const int*   seq   = (const int*)d_in[0];
    const float* embed = (const float*)d_in[1];
    const float* W1    = (const float*)d_in[2];
    const float* b1    = (const float*)d_in[3];
    const float* W2    = (const float*)d_in[4];
    const float* b2    = (const float*)d_in[5];
    const float* gamma = (const float*)d_in[6];
    const float* beta  = (const float*)d_in[7];
    const float* Wq    = (const float*)d_in[8];
    const float* bq    = (const float*)d_in[9];
    const float* Wo    = (const float*)d_in[10];
    const float* bo    = (const float*)d_in[11];
    float* out = (float*)d_out;
    (void)in_sizes; (void)n_in; (void)out_size; (void)d_ws; (void)ws_size;

    slot_fused<<<256, 512, 0, stream>>>(seq, embed, W1, b1, W2, b2,
                                        gamma, beta, Wq, bq, Wo, bo, out);
}

// Round 2
// 24.272 us; speedup vs baseline: 1.9988x; 1.9988x over previous
//
#include <hip/hip_runtime.h>
#include <math.h>

#define EPS 1e-5f

// One block per batch row (grid 256 == CU count; redundant table rebuild is
// wall-clock free). 1024 threads = 16 waves. All matmul operands staged in
// LDS; micro-tiled register accumulators; LN/score fused via 16-lane shfl
// reductions; epilogue collapsed into wave 0 with register shfl.
__global__ __launch_bounds__(1024, 4) void slot_fused(
    const int* __restrict__ seq,
    const float* __restrict__ embed,
    const float* __restrict__ W1, const float* __restrict__ b1,
    const float* __restrict__ W2, const float* __restrict__ b2,
    const float* __restrict__ gamma, const float* __restrict__ beta,
    const float* __restrict__ Wq, const float* __restrict__ bq,
    const float* __restrict__ Wo, const float* __restrict__ bo,
    float* __restrict__ out)
{
    __shared__ float E[64][68];      // embed rows (pad 68: 16B-aligned, bank-spread)
    __shared__ float W1s[64][128];
    __shared__ float W2s[128][64];
    __shared__ float Us[64][132];    // relu(E@W1+b1) (pad 132)
    __shared__ float HS[64][68];     // layernormed table
    __shared__ int   hist[16][64];   // per-wave sub-histograms
    __shared__ float sc[64];         // gate score (norm)
    __shared__ int   cnt[64];        // selected slot count per token
    __shared__ int   tlast;

    const int tid = threadIdx.x;
    const int wv  = tid >> 6;
    const int b   = blockIdx.x;
    const int* row = seq + b * 4096;

    // ---- P0a: zero hist, fetch seq chunk to regs, stage E/W1/W2 to LDS ----
    hist[wv][tid & 63] = 0;

    int4 sv = make_int4(0, 0, 0, 0);
    const bool have4 = (tid < 1023);
    int tail = 0;
    if (have4) sv = reinterpret_cast<const int4*>(row)[tid];
    if (tid == 1023) { tail = row[4092]; tlast = row[4095]; }

    {
        float4 ev = reinterpret_cast<const float4*>(embed)[tid];   // 1024 f4 = 16KB
        int t = tid >> 4, j4 = (tid & 15) << 2;
        *reinterpret_cast<float4*>(&E[t][j4]) = ev;

        float4 w1a = reinterpret_cast<const float4*>(W1)[tid];
        float4 w1b = reinterpret_cast<const float4*>(W1)[tid + 1024];
        reinterpret_cast<float4*>(&W1s[0][0])[tid]        = w1a;
        reinterpret_cast<float4*>(&W1s[0][0])[tid + 1024] = w1b;

        float4 w2a = reinterpret_cast<const float4*>(W2)[tid];
        float4 w2b = reinterpret_cast<const float4*>(W2)[tid + 1024];
        reinterpret_cast<float4*>(&W2s[0][0])[tid]        = w2a;
        reinterpret_cast<float4*>(&W2s[0][0])[tid + 1024] = w2b;
    }
    __syncthreads();

    // ---- P0b: histogram (overlaps with P1 compute; drains by next barrier) ----
    if (have4) {
        atomicAdd(&hist[wv][sv.x], 1);
        atomicAdd(&hist[wv][sv.y], 1);
        atomicAdd(&hist[wv][sv.z], 1);
        atomicAdd(&hist[wv][sv.w], 1);
    }
    if (tid == 1023) atomicAdd(&hist[wv][tail], 1);

    // ---- P1: U = relu(E@W1+b1). thread = (token t, kslice ks); 8 outputs:
    //      k in {4ks..4ks+3} and {64+4ks..64+4ks+3} (contiguous b128 slices) ----
    {
        int t = tid >> 4, ks = tid & 15;
        int kla = ks << 2, klb = 64 + (ks << 2);
        float4 ba = *reinterpret_cast<const float4*>(&b1[kla]);
        float4 bb = *reinterpret_cast<const float4*>(&b1[klb]);
        float a0 = ba.x, a1 = ba.y, a2 = ba.z, a3 = ba.w;
        float a4 = bb.x, a5 = bb.y, a6 = bb.z, a7 = bb.w;
        #pragma unroll 8
        for (int j = 0; j < 64; ++j) {
            float e = E[t][j];                               // 16-lane broadcast
            float4 wA = *reinterpret_cast<const float4*>(&W1s[j][kla]);
            float4 wB = *reinterpret_cast<const float4*>(&W1s[j][klb]);
            a0 = fmaf(e, wA.x, a0); a1 = fmaf(e, wA.y, a1);
            a2 = fmaf(e, wA.z, a2); a3 = fmaf(e, wA.w, a3);
            a4 = fmaf(e, wB.x, a4); a5 = fmaf(e, wB.y, a5);
            a6 = fmaf(e, wB.z, a6); a7 = fmaf(e, wB.w, a7);
        }
        *reinterpret_cast<float4*>(&Us[t][kla]) =
            make_float4(fmaxf(a0,0.f), fmaxf(a1,0.f), fmaxf(a2,0.f), fmaxf(a3,0.f));
        *reinterpret_cast<float4*>(&Us[t][klb]) =
            make_float4(fmaxf(a4,0.f), fmaxf(a5,0.f), fmaxf(a6,0.f), fmaxf(a7,0.f));
    }
    __syncthreads();

    // ---- P2: H = E + U@W2 + b2, fused LN -> HS, fused gate score ----
    {
        int t = tid >> 4, ks = tid & 15;
        int j0 = ks << 2;
        float4 bb = *reinterpret_cast<const float4*>(&b2[j0]);
        float h0 = bb.x, h1 = bb.y, h2 = bb.z, h3 = bb.w;
        #pragma unroll 8
        for (int k = 0; k < 128; ++k) {
            float u = Us[t][k];                              // 16-lane broadcast
            float4 w = *reinterpret_cast<const float4*>(&W2s[k][j0]);
            h0 = fmaf(u, w.x, h0); h1 = fmaf(u, w.y, h1);
            h2 = fmaf(u, w.z, h2); h3 = fmaf(u, w.w, h3);
        }
        float4 ee = *reinterpret_cast<const float4*>(&E[t][j0]);
        h0 += ee.x; h1 += ee.y; h2 += ee.z; h3 += ee.w;

        float s = h0 + h1 + h2 + h3;
        #pragma unroll
        for (int off = 1; off < 16; off <<= 1) s += __shfl_xor(s, off);
        float mu = s * (1.f / 64.f);
        float d0 = h0 - mu, d1 = h1 - mu, d2 = h2 - mu, d3 = h3 - mu;
        float v = d0*d0 + d1*d1 + d2*d2 + d3*d3;
        #pragma unroll
        for (int off = 1; off < 16; off <<= 1) v += __shfl_xor(v, off);
        float rstd = rsqrtf(v * (1.f / 64.f) + EPS);

        float4 gg = *reinterpret_cast<const float4*>(&gamma[j0]);
        float4 be = *reinterpret_cast<const float4*>(&beta[j0]);
        float hs0 = d0 * rstd * gg.x + be.x;
        float hs1 = d1 * rstd * gg.y + be.y;
        float hs2 = d2 * rstd * gg.z + be.z;
        float hs3 = d3 * rstd * gg.w + be.w;
        *reinterpret_cast<float4*>(&HS[t][j0]) = make_float4(hs0, hs1, hs2, hs3);

        float ss = hs0*hs0 + hs1*hs1 + hs2*hs2 + hs3*hs3;
        #pragma unroll
        for (int off = 1; off < 16; off <<= 1) ss += __shfl_xor(ss, off);
        if (ks == 0) sc[t] = sqrtf(ss);
    }
    __syncthreads();

    // ---- P3: wave0: q = HS[tlast]@Wq+bq (regs); wave1: merge hist + counts ----
    float q_reg = 0.f;
    if (wv == 0) {
        int j = tid;
        int tl = tlast;
        float acc = bq[j];
        #pragma unroll 8
        for (int k = 0; k < 64; ++k)
            acc = fmaf(HS[tl][k], Wq[k * 64 + j], acc);      // Wq L2-resident
        q_reg = acc;
    } else if (wv == 1) {
        int t = tid & 63;
        int h = 0;
        #pragma unroll
        for (int w = 0; w < 16; ++w) h += hist[w][t];
        float my = sc[t];
        int S = 0;                    // occurrences of tokens ranked before t
        for (int t2 = 0; t2 < 64; ++t2) {
            float s2 = sc[t2];
            int   h2 = __shfl(h, t2);
            bool before = (s2 > my) || (s2 == my && t2 < t);
            if (before) S += h2;
        }
        int rem = 64 - S;
        rem = rem < 0 ? 0 : rem;
        cnt[t] = h < rem ? h : rem;
    }
    __syncthreads();

    // ---- P4: wave0 only: logits -> softmax(w/ multiplicity) -> ctx -> out ----
    if (wv == 0) {
        int t = tid;   // lane plays role of token t, then output j
        float acc = 0.f;
        #pragma unroll 8
        for (int k = 0; k < 64; ++k) {
            float qk = __shfl(q_reg, k);
            acc = fmaf(qk, HS[t][k], acc);
        }
        float logit = acc * 0.125f;                          // / sqrt(64)
        int c = cnt[t];
        float lm = (c > 0) ? logit : -1e30f;
        #pragma unroll
        for (int off = 1; off < 64; off <<= 1) lm = fmaxf(lm, __shfl_xor(lm, off));
        float wvv = (c > 0) ? (float)c * __expf(logit - lm) : 0.f;
        float z = wvv;
        #pragma unroll
        for (int off = 1; off < 64; off <<= 1) z += __shfl_xor(z, off);
        float w_reg = wvv / z;                               // lane t holds wgt_t

        float cacc = 0.f;                                    // ctx[j], j = tid
        #pragma unroll 8
        for (int t2 = 0; t2 < 64; ++t2) {
            float wt = __shfl(w_reg, t2);
            cacc = fmaf(wt, HS[t2][tid], cacc);
        }

        float oacc = bo[tid];
        #pragma unroll 8
        for (int k = 0; k < 64; ++k) {
            float ck = __shfl(cacc, k);
            oacc = fmaf(ck, Wo[k * 64 + tid], oacc);         // Wo L2-resident
        }
        out[b * 64 + tid] = oacc;
    }
}

extern "C" void kernel_launch(void* const* d_in, const int* in_sizes, int n_in,
                              void* d_out, int out_size, void* d_ws, size_t ws_size,
                              hipStream_t stream) {
    const int*   seq   = (const int*)d_in[0];
    const float* embed = (const float*)d_in[1];
    const float* W1    = (const float*)d_in[2];
    const float* b1    = (const float*)d_in[3];
    const float* W2    = (const float*)d_in[4];
    const float* b2    = (const float*)d_in[5];
    const float* gamma = (const float*)d_in[6];
    const float* beta  = (const float*)d_in[7];
    const float* Wq    = (const float*)d_in[8];
    const float* bq    = (const float*)d_in[9];
    const float* Wo    = (const float*)d_in[10];
    const float* bo    = (const float*)d_in[11];
    float* out = (float*)d_out;
    (void)in_sizes; (void)n_in; (void)out_size; (void)d_ws; (void)ws_size;

    slot_fused<<<256, 1024, 0, stream>>>(seq, embed, W1, b1, W2, b2,
                                         gamma, beta, Wq, bq, Wo, bo, out);
}

// Round 3
// 16.977 us; speedup vs baseline: 2.8576x; 1.4297x over previous
//
#include <hip/hip_runtime.h>
#include <math.h>

#define EPS 1e-5f

// ---------------- Kernel A: build the 64-token table ----------------
// The whole network up to `hs` depends only on the token id (VOCAB=64).
// 64 blocks, one token each. Writes wsf[0..4095] = HS[64][64] row-major,
// wsf[4096..4159] = gate score per token.
__global__ __launch_bounds__(256) void build_table(
    const float* __restrict__ embed,
    const float* __restrict__ W1, const float* __restrict__ b1,
    const float* __restrict__ W2, const float* __restrict__ b2,
    const float* __restrict__ gamma, const float* __restrict__ beta,
    float* __restrict__ wsf)
{
    __shared__ float W1s[64][128];
    __shared__ float W2s[128][64];
    __shared__ float e[64];
    __shared__ float Up[2][128];
    __shared__ float U[128];
    __shared__ float Hp[4][64];

    const int tid = threadIdx.x;
    const int t   = blockIdx.x;

    // Bulk-stage W1 (32KB) + W2 (32KB): 16 independent float4 loads/thread,
    // one wait -> ~one cold-HBM latency total.
    #pragma unroll
    for (int i = 0; i < 8; ++i) {
        reinterpret_cast<float4*>(&W1s[0][0])[tid + 256 * i] =
            reinterpret_cast<const float4*>(W1)[tid + 256 * i];
        reinterpret_cast<float4*>(&W2s[0][0])[tid + 256 * i] =
            reinterpret_cast<const float4*>(W2)[tid + 256 * i];
    }
    if (tid < 64) e[tid] = embed[t * 64 + tid];
    __syncthreads();

    // U = relu(e@W1 + b1): thread (j = tid&127, h = tid>>7) does a 32-K half.
    {
        int j = tid & 127, h = tid >> 7;
        int k0 = h << 5;
        float acc = 0.f;
        #pragma unroll 8
        for (int k = 0; k < 32; ++k)
            acc = fmaf(e[k0 + k], W1s[k0 + k][j], acc);
        Up[h][j] = acc;
    }
    __syncthreads();
    if (tid < 128) U[tid] = fmaxf(b1[tid] + Up[0][tid] + Up[1][tid], 0.f);
    __syncthreads();

    // H = e + U@W2 + b2: thread (j = tid&63, q = tid>>6) does a 32-K quarter.
    {
        int j = tid & 63, qd = tid >> 6;
        int k0 = qd << 5;
        float acc = 0.f;
        #pragma unroll 8
        for (int k = 0; k < 32; ++k)
            acc = fmaf(U[k0 + k], W2s[k0 + k][j], acc);
        Hp[qd][j] = acc;
    }
    __syncthreads();

    // LN + gamma/beta + gate norm, one wave (lane = hidden dim j).
    if (tid < 64) {
        float h = e[tid] + b2[tid] + Hp[0][tid] + Hp[1][tid] + Hp[2][tid] + Hp[3][tid];
        float s = h;
        #pragma unroll
        for (int off = 1; off < 64; off <<= 1) s += __shfl_xor(s, off);
        float mu = s * (1.f / 64.f);
        float d = h - mu;
        float v = d * d;
        #pragma unroll
        for (int off = 1; off < 64; off <<= 1) v += __shfl_xor(v, off);
        float rstd = rsqrtf(v * (1.f / 64.f) + EPS);
        float hs = d * rstd * gamma[tid] + beta[tid];
        wsf[t * 64 + tid] = hs;
        float ss = hs * hs;
        #pragma unroll
        for (int off = 1; off < 64; off <<= 1) ss += __shfl_xor(ss, off);
        if (tid == 0) wsf[4096 + t] = sqrtf(ss);
    }
}

// ---------------- Kernel B: per-batch histogram + epilogue ----------------
// One block per batch row. top_k(64) over positions == greedy token ranking
// by score; slot multiplicity = clipped histogram count. Softmax with
// multiplicity, ctx, output projection.
__global__ __launch_bounds__(256) void slot_epilogue(
    const int* __restrict__ seq,
    const float* __restrict__ Wq, const float* __restrict__ bq,
    const float* __restrict__ Wo, const float* __restrict__ bo,
    const float* __restrict__ wsf,
    float* __restrict__ out)
{
    __shared__ float HS[64][65];    // pad 65 -> all row/col patterns 2-way max
    __shared__ int   hist[4][64];
    __shared__ float qv[64];
    __shared__ int   tlast_s;

    const int tid = threadIdx.x;
    const int wv  = tid >> 6;
    const int ln  = tid & 63;
    const int b   = blockIdx.x;
    const int* row = seq + b * 4096;

    hist[wv][ln] = 0;

    // Register prefetch (fully unrolled -> stays in VGPRs): wave0 takes the
    // Wo column + bo + score, wave1 takes the Wq column + bq. Overlaps with
    // HS staging and the histogram below.
    float wcol[64];
    float bias = 0.f, sc_r = 0.f;
    if (wv == 0) {
        #pragma unroll
        for (int k = 0; k < 64; ++k) wcol[k] = Wo[k * 64 + ln];
        bias = bo[ln];
        sc_r = wsf[4096 + ln];
    } else if (wv == 1) {
        #pragma unroll
        for (int k = 0; k < 64; ++k) wcol[k] = Wq[k * 64 + ln];
        bias = bq[ln];
    }

    // Stage HS table (16KB) from ws.
    #pragma unroll
    for (int i = 0; i < 4; ++i) {
        int idx4 = tid + 256 * i;                 // float4 index 0..1023
        float4 v = reinterpret_cast<const float4*>(wsf)[idx4];
        int t  = idx4 >> 4;
        int j0 = (idx4 & 15) << 2;
        HS[t][j0] = v.x; HS[t][j0 + 1] = v.y; HS[t][j0 + 2] = v.z; HS[t][j0 + 3] = v.w;
    }

    // Histogram positions 0..4092 (content = hs[:, :-3]).
    #pragma unroll
    for (int i = 0; i < 4; ++i) {
        int idx = tid + 256 * i;
        if (idx < 1023) {
            int4 v = reinterpret_cast<const int4*>(row)[idx];
            atomicAdd(&hist[wv][v.x], 1);
            atomicAdd(&hist[wv][v.y], 1);
            atomicAdd(&hist[wv][v.z], 1);
            atomicAdd(&hist[wv][v.w], 1);
        }
    }
    if (tid == 0) {
        atomicAdd(&hist[0][row[4092]], 1);
        tlast_s = row[4095];
    }
    __syncthreads();

    // Phase 1: wave0 -> slot counts (regs); wave1 -> q = HS[tl]@Wq + bq.
    int cnt_i = 0;
    if (wv == 0) {
        int h = hist[0][ln] + hist[1][ln] + hist[2][ln] + hist[3][ln];
        float my = sc_r;
        int S = 0;   // occurrences of tokens ranked strictly before ln
        for (int t2 = 0; t2 < 64; ++t2) {
            float s2 = __shfl(sc_r, t2);
            int   h2 = __shfl(h, t2);
            bool before = (s2 > my) || (s2 == my && t2 < ln);
            if (before) S += h2;
        }
        int rem = 64 - S;
        rem = rem < 0 ? 0 : rem;
        cnt_i = h < rem ? h : rem;
    } else if (wv == 1) {
        int tl = tlast_s;
        float acc = bias;
        #pragma unroll
        for (int k = 0; k < 64; ++k)
            acc = fmaf(HS[tl][k], wcol[k], acc);   // HS broadcast, wcol in regs
        qv[ln] = acc;
    }
    __syncthreads();

    // Phase 2: wave0 only: logits -> softmax(w/ multiplicity) -> ctx -> out.
    if (wv == 0) {
        float acc = 0.f;
        #pragma unroll 8
        for (int k = 0; k < 64; ++k)
            acc = fmaf(qv[k], HS[ln][k], acc);     // lane=row, pad-65: conflict-free
        float logit = acc * 0.125f;                // / sqrt(64)
        float lm = (cnt_i > 0) ? logit : -1e30f;
        #pragma unroll
        for (int off = 1; off < 64; off <<= 1) lm = fmaxf(lm, __shfl_xor(lm, off));
        float wvv = (cnt_i > 0) ? (float)cnt_i * __expf(logit - lm) : 0.f;
        float z = wvv;
        #pragma unroll
        for (int off = 1; off < 64; off <<= 1) z += __shfl_xor(z, off);
        float w_reg = wvv / z;                     // lane t holds weight_t

        float cacc = 0.f;                          // ctx[ln]
        #pragma unroll 8
        for (int t2 = 0; t2 < 64; ++t2)
            cacc = fmaf(__shfl(w_reg, t2), HS[t2][ln], cacc);

        float oacc = bias;                         // out[ln]
        #pragma unroll
        for (int k = 0; k < 64; ++k)
            oacc = fmaf(__shfl(cacc, k), wcol[k], oacc);
        out[b * 64 + ln] = oacc;
    }
}

extern "C" void kernel_launch(void* const* d_in, const int* in_sizes, int n_in,
                              void* d_out, int out_size, void* d_ws, size_t ws_size,
                              hipStream_t stream) {
    const int*   seq   = (const int*)d_in[0];
    const float* embed = (const float*)d_in[1];
    const float* W1    = (const float*)d_in[2];
    const float* b1    = (const float*)d_in[3];
    const float* W2    = (const float*)d_in[4];
    const float* b2    = (const float*)d_in[5];
    const float* gamma = (const float*)d_in[6];
    const float* beta  = (const float*)d_in[7];
    const float* Wq    = (const float*)d_in[8];
    const float* bq    = (const float*)d_in[9];
    const float* Wo    = (const float*)d_in[10];
    const float* bo    = (const float*)d_in[11];
    float* out = (float*)d_out;
    float* wsf = (float*)d_ws;
    (void)in_sizes; (void)n_in; (void)out_size; (void)ws_size;

    build_table<<<64, 256, 0, stream>>>(embed, W1, b1, W2, b2, gamma, beta, wsf);
    slot_epilogue<<<256, 256, 0, stream>>>(seq, Wq, bq, Wo, bo, wsf, out);
}

// Round 4
// 16.939 us; speedup vs baseline: 2.8641x; 1.0023x over previous
//
#include <hip/hip_runtime.h>
#include <math.h>

#define EPS 1e-5f

// ws layout (floats): [0,4096) HS table row-major; [4096,4160) gate scores.
// ws ints (offset 4160 floats): [0,16384) per-row histograms; [16384,16640) tlast.

// ---------------- Kernel A: table (blocks 0..63) + histograms (64..319) ----
__global__ __launch_bounds__(256) void table_and_hist(
    const int* __restrict__ seq,
    const float* __restrict__ embed,
    const float* __restrict__ W1, const float* __restrict__ b1,
    const float* __restrict__ W2, const float* __restrict__ b2,
    const float* __restrict__ gamma, const float* __restrict__ beta,
    float* __restrict__ wsf, int* __restrict__ wsi_hist,
    int* __restrict__ wsi_tlast)
{
    const int tid = threadIdx.x;

    if (blockIdx.x < 64) {
        // ---------- build one token's table row ----------
        __shared__ float W1s[64][128];
        __shared__ float W2s[128][64];
        __shared__ float e[64];
        __shared__ float Up[2][128];
        __shared__ float U[128];
        __shared__ float Hp[4][64];

        const int t = blockIdx.x;

        #pragma unroll
        for (int i = 0; i < 8; ++i) {
            reinterpret_cast<float4*>(&W1s[0][0])[tid + 256 * i] =
                reinterpret_cast<const float4*>(W1)[tid + 256 * i];
            reinterpret_cast<float4*>(&W2s[0][0])[tid + 256 * i] =
                reinterpret_cast<const float4*>(W2)[tid + 256 * i];
        }
        if (tid < 64) e[tid] = embed[t * 64 + tid];
        __syncthreads();

        {   // U = relu(e@W1 + b1), split-K halves
            int j = tid & 127, h = tid >> 7;
            int k0 = h << 5;
            float acc = 0.f;
            #pragma unroll 8
            for (int k = 0; k < 32; ++k)
                acc = fmaf(e[k0 + k], W1s[k0 + k][j], acc);
            Up[h][j] = acc;
        }
        __syncthreads();
        if (tid < 128) U[tid] = fmaxf(b1[tid] + Up[0][tid] + Up[1][tid], 0.f);
        __syncthreads();

        {   // H = e + U@W2 + b2, split-K quarters
            int j = tid & 63, qd = tid >> 6;
            int k0 = qd << 5;
            float acc = 0.f;
            #pragma unroll 8
            for (int k = 0; k < 32; ++k)
                acc = fmaf(U[k0 + k], W2s[k0 + k][j], acc);
            Hp[qd][j] = acc;
        }
        __syncthreads();

        if (tid < 64) {   // LN + gamma/beta + gate norm
            float h = e[tid] + b2[tid] + Hp[0][tid] + Hp[1][tid] + Hp[2][tid] + Hp[3][tid];
            float s = h;
            #pragma unroll
            for (int off = 1; off < 64; off <<= 1) s += __shfl_xor(s, off);
            float mu = s * (1.f / 64.f);
            float d = h - mu;
            float v = d * d;
            #pragma unroll
            for (int off = 1; off < 64; off <<= 1) v += __shfl_xor(v, off);
            float rstd = rsqrtf(v * (1.f / 64.f) + EPS);
            float hs = d * rstd * gamma[tid] + beta[tid];
            wsf[t * 64 + tid] = hs;
            float ss = hs * hs;
            #pragma unroll
            for (int off = 1; off < 64; off <<= 1) ss += __shfl_xor(ss, off);
            if (tid == 0) wsf[4096 + t] = sqrtf(ss);
        }
    } else {
        // ---------- histogram one batch row (positions 0..4092) ----------
        __shared__ int hist[4][64];
        const int b = blockIdx.x - 64;
        const int wv = tid >> 6, ln = tid & 63;
        const int* row = seq + b * 4096;

        hist[wv][ln] = 0;
        __syncthreads();

        #pragma unroll
        for (int i = 0; i < 4; ++i) {
            int idx = tid + 256 * i;
            if (idx < 1023) {
                int4 v = reinterpret_cast<const int4*>(row)[idx];
                atomicAdd(&hist[wv][v.x], 1);
                atomicAdd(&hist[wv][v.y], 1);
                atomicAdd(&hist[wv][v.z], 1);
                atomicAdd(&hist[wv][v.w], 1);
            }
        }
        if (tid == 0) {
            atomicAdd(&hist[0][row[4092]], 1);
            wsi_tlast[b] = row[4095];
        }
        __syncthreads();

        if (tid < 64)
            wsi_hist[b * 64 + tid] =
                hist[0][tid] + hist[1][tid] + hist[2][tid] + hist[3][tid];
    }
}

// ---------------- Kernel B: tiny per-row epilogue ----------------
__global__ __launch_bounds__(256) void slot_epilogue(
    const float* __restrict__ Wq, const float* __restrict__ bq,
    const float* __restrict__ Wo, const float* __restrict__ bo,
    const float* __restrict__ wsf, const int* __restrict__ wsi_hist,
    const int* __restrict__ wsi_tlast,
    float* __restrict__ out)
{
    __shared__ float HS[64][65];    // pad 65: row+col access conflict-free
    __shared__ float qv[64];

    const int tid = threadIdx.x;
    const int wv  = tid >> 6;
    const int ln  = tid & 63;
    const int b   = blockIdx.x;

    // Register prefetch: wave0 = Wo column + bo + score + hist count;
    // wave1 = Wq column + bq + tlast. Fully unrolled -> VGPRs.
    float wcol[64];
    float bias = 0.f, sc_r = 0.f;
    int h = 0, tl = 0;
    if (wv == 0) {
        #pragma unroll
        for (int k = 0; k < 64; ++k) wcol[k] = Wo[k * 64 + ln];
        bias = bo[ln];
        sc_r = wsf[4096 + ln];
        h    = wsi_hist[b * 64 + ln];
    } else if (wv == 1) {
        #pragma unroll
        for (int k = 0; k < 64; ++k) wcol[k] = Wq[k * 64 + ln];
        bias = bq[ln];
        tl   = wsi_tlast[b];
    }

    // Stage HS table (16KB, L2-resident) — all 4 waves.
    #pragma unroll
    for (int i = 0; i < 4; ++i) {
        int idx4 = tid + 256 * i;                 // float4 index 0..1023
        float4 v = reinterpret_cast<const float4*>(wsf)[idx4];
        int t  = idx4 >> 4;
        int j0 = (idx4 & 15) << 2;
        HS[t][j0] = v.x; HS[t][j0+1] = v.y; HS[t][j0+2] = v.z; HS[t][j0+3] = v.w;
    }
    __syncthreads();

    // Phase 1: wave0 -> slot counts; wave1 -> q = HS[tl]@Wq + bq.
    int cnt_i = 0;
    if (wv == 0) {
        float my = sc_r;
        int S = 0;   // occurrences of tokens ranked strictly before ln
        for (int t2 = 0; t2 < 64; ++t2) {
            float s2 = __shfl(sc_r, t2);
            int   h2 = __shfl(h, t2);
            bool before = (s2 > my) || (s2 == my && t2 < ln);
            if (before) S += h2;
        }
        int rem = 64 - S;
        rem = rem < 0 ? 0 : rem;
        cnt_i = h < rem ? h : rem;
    } else if (wv == 1) {
        float acc = bias;
        #pragma unroll
        for (int k = 0; k < 64; ++k)
            acc = fmaf(HS[tl][k], wcol[k], acc);   // HS broadcast, wcol in regs
        qv[ln] = acc;
    }
    __syncthreads();

    // Phase 2: wave0: logits -> softmax(w/ multiplicity) -> ctx -> out.
    if (wv == 0) {
        float acc = 0.f;
        #pragma unroll 8
        for (int k = 0; k < 64; ++k)
            acc = fmaf(qv[k], HS[ln][k], acc);     // pad-65: conflict-free cols
        float logit = acc * 0.125f;                // / sqrt(64)
        float lm = (cnt_i > 0) ? logit : -1e30f;
        #pragma unroll
        for (int off = 1; off < 64; off <<= 1) lm = fmaxf(lm, __shfl_xor(lm, off));
        float wvv = (cnt_i > 0) ? (float)cnt_i * __expf(logit - lm) : 0.f;
        float z = wvv;
        #pragma unroll
        for (int off = 1; off < 64; off <<= 1) z += __shfl_xor(z, off);
        float w_reg = wvv / z;                     // lane t holds weight_t

        float cacc = 0.f;                          // ctx[ln]
        #pragma unroll 8
        for (int t2 = 0; t2 < 64; ++t2)
            cacc = fmaf(__shfl(w_reg, t2), HS[t2][ln], cacc);

        float oacc = bias;                         // out[ln]
        #pragma unroll
        for (int k = 0; k < 64; ++k)
            oacc = fmaf(__shfl(cacc, k), wcol[k], oacc);
        out[b * 64 + ln] = oacc;
    }
}

extern "C" void kernel_launch(void* const* d_in, const int* in_sizes, int n_in,
                              void* d_out, int out_size, void* d_ws, size_t ws_size,
                              hipStream_t stream) {
    const int*   seq   = (const int*)d_in[0];
    const float* embed = (const float*)d_in[1];
    const float* W1    = (const float*)d_in[2];
    const float* b1    = (const float*)d_in[3];
    const float* W2    = (const float*)d_in[4];
    const float* b2    = (const float*)d_in[5];
    const float* gamma = (const float*)d_in[6];
    const float* beta  = (const float*)d_in[7];
    const float* Wq    = (const float*)d_in[8];
    const float* bq    = (const float*)d_in[9];
    const float* Wo    = (const float*)d_in[10];
    const float* bo    = (const float*)d_in[11];
    float* out = (float*)d_out;
    float* wsf = (float*)d_ws;
    int*   wsi_hist  = (int*)(wsf + 4160);
    int*   wsi_tlast = wsi_hist + 256 * 64;
    (void)in_sizes; (void)n_in; (void)out_size; (void)ws_size;

    table_and_hist<<<320, 256, 0, stream>>>(seq, embed, W1, b1, W2, b2,
                                            gamma, beta, wsf, wsi_hist, wsi_tlast);
    slot_epilogue<<<256, 256, 0, stream>>>(Wq, bq, Wo, bo, wsf, wsi_hist,
                                           wsi_tlast, out);
}